// Round 5
// baseline (1417.617 us; speedup 1.0000x reference)
//
#include <hip/hip_runtime.h>

#define NN 50000
#define FIN 128
#define HC 256
#define NH 8
#define NE 800000
#define WROW 136          // padded LDS row (shorts)
#define NBLK 1008         // 4 blocks/CU x 252 CUs  (capacity 1024 at launch_bounds(256,4))
#define NT 391            // gemm tiles of 128 rows
#define NBCH 391          // scan chunks of 128

typedef __attribute__((ext_vector_type(8))) short short8;
typedef __attribute__((ext_vector_type(4))) short short4v;
typedef __attribute__((ext_vector_type(4))) float floatx4;

__device__ __forceinline__ float bf2f(unsigned short u) {
    union { unsigned int i; float f; } v; v.i = ((unsigned int)u) << 16; return v.f;
}
__device__ __forceinline__ unsigned short f2bf(float f) {
    union { float f; unsigned int i; } v; v.f = f;
    unsigned int r = v.i + 0x7fffu + ((v.i >> 16) & 1u);
    return (unsigned short)(r >> 16);
}
__device__ __forceinline__ float lrelu(float x) { return x > 0.f ? x : 0.2f * x; }
__device__ __forceinline__ float ldf(const void* p, int f32, long long i) {
    return f32 ? ((const float*)p)[i] : bf2f(((const unsigned short*)p)[i]);
}
__device__ __forceinline__ int lde(const int* ei, int i64, long long i) {
    return i64 ? (int)((const long long*)ei)[i] : ei[i];
}
__device__ __forceinline__ float sel8(const float s[2][4], int t2, int rr) {
    float a0 = t2 ? s[1][0] : s[0][0];
    float a1 = t2 ? s[1][1] : s[0][1];
    float a2 = t2 ? s[1][2] : s[0][2];
    float a3 = t2 ? s[1][3] : s[0][3];
    return (rr == 0) ? a0 : ((rr == 1) ? a1 : ((rr == 2) ? a2 : a3));
}

// grid barrier: single-use counter per slot, device scope (works across XCDs)
__device__ __forceinline__ void gridbar(unsigned int* bar, int slot) {
    __syncthreads();
    if (threadIdx.x == 0) {
        __threadfence();
        __hip_atomic_fetch_add(&bar[slot], 1u, __ATOMIC_RELEASE, __HIP_MEMORY_SCOPE_AGENT);
        while (__hip_atomic_load(&bar[slot], __ATOMIC_ACQUIRE, __HIP_MEMORY_SCOPE_AGENT) < (unsigned)gridDim.x)
            __builtin_amdgcn_s_sleep(2);
    }
    __syncthreads();
    __threadfence();
}

__global__ __launch_bounds__(256, 4) void k_fused(
        const void* __restrict__ x, const int* __restrict__ ei,
        const void* __restrict__ dpm, const void* __restrict__ dps,
        const void* __restrict__ W, const void* __restrict__ as_,
        const void* __restrict__ ad_, const void* __restrict__ bs_,
        unsigned short* __restrict__ h, float* __restrict__ a_src,
        float* __restrict__ a_dst, int* __restrict__ ptr,
        unsigned short* __restrict__ wt, float* __restrict__ attc,
        int* __restrict__ bsum, unsigned int* __restrict__ csr,
        unsigned int* __restrict__ bar, void* __restrict__ out) {
    __shared__ unsigned short lwt[128 * WROW];   // 34,816 B (4 blocks/CU fit in 160K)
    __shared__ int ssc[4];
    __shared__ int s_bad, s_nz;

    const int tid = threadIdx.x;
    const int b = blockIdx.x;

    // ---- local dtype flags (every block; reads same leading words, L2-broadcast) ----
    if (tid == 0) { s_bad = 0; s_nz = 0; }
    __syncthreads();
    {
        unsigned int wv = ((const unsigned int*)dpm)[tid];     // fp32 dp_mask words: 0 or 2.5f
        if (wv != 0u && wv != 0x40200000u) atomicAdd(&s_bad, 1);
        if (((const unsigned int*)ei)[2 * tid + 1] != 0u) atomicAdd(&s_nz, 1);
    }
    __syncthreads();
    const int f32 = (s_bad == 0) ? 1 : 0;
    const int i64 = (s_nz == 0) ? 1 : 0;

    // ---- P0: zero ptr; canonicalize W^T (bf16) + attc (fp32) ----
    for (int i = b * 256 + tid; i < NN; i += NBLK * 256) ptr[i] = 0;
    for (int idx = b * 256 + tid; idx < FIN * HC + 768; idx += NBLK * 256) {
        if (idx < FIN * HC) {
            int c = idx >> 7, k = idx & 127;
            wt[idx] = f2bf(ldf(W, f32, (long long)k * HC + c));
        } else {
            int j = idx - FIN * HC;
            if (j < 256)      attc[j] = ldf(as_, f32, j);
            else if (j < 512) attc[j] = ldf(ad_, f32, j - 256);
            else              attc[j] = ldf(bs_, f32, j - 512);
        }
    }
    gridbar(bar, 0);

    // ---- P1: blocks < NT do GEMM+scores tile; blocks >= NT do degree histogram ----
    if (b < NT) {
        const int lane = tid & 63;
        const int wave = tid >> 6;
        const int lrow = lane & 15;
        const int quad = lane >> 4;
        const int row0w = b * 128 + wave * 32;

        short8 a[2][4];
        #pragma unroll
        for (int t = 0; t < 2; t++)
            #pragma unroll
            for (int q = 0; q < 4; q++)
                #pragma unroll
                for (int j = 0; j < 8; j++) a[t][q][j] = 0;

        #pragma unroll
        for (int t = 0; t < 2; t++) {
            int row = row0w + t * 16 + lrow;
            if (row < NN) {
                if (f32) {
                    const float* xp = (const float*)x + (long long)row * FIN + quad * 8;
                    #pragma unroll
                    for (int q = 0; q < 4; q++) {
                        floatx4 u0 = *(const floatx4*)(xp + q * 32);
                        floatx4 u1 = *(const floatx4*)(xp + q * 32 + 4);
                        #pragma unroll
                        for (int j = 0; j < 4; j++) {
                            a[t][q][j]     = (short)f2bf(u0[j]);
                            a[t][q][j + 4] = (short)f2bf(u1[j]);
                        }
                    }
                } else {
                    const unsigned short* xp = (const unsigned short*)x + (long long)row * FIN + quad * 8;
                    #pragma unroll
                    for (int q = 0; q < 4; q++) a[t][q] = *(const short8*)(xp + q * 32);
                }
            }
        }

        float sS[2][4], sD[2][4];
        for (int st = 0; st < 2; st++) {       // two 128-col stages of W in LDS
            __syncthreads();
            {   // copy wt rows [st*128, st*128+128) -> lwt
                int r = tid >> 1, half = tid & 1;
                const short8* s8 = (const short8*)(wt + ((long long)(st * 128 + r)) * FIN + half * 64);
                short8* d8 = (short8*)(lwt + r * WROW + half * 64);
                #pragma unroll
                for (int j = 0; j < 8; j++) d8[j] = s8[j];
            }
            __syncthreads();
            #pragma unroll
            for (int c2 = 0; c2 < 8; c2++) {
                int ct = st * 8 + c2;
                if ((c2 & 1) == 0) {
                    #pragma unroll
                    for (int t = 0; t < 2; t++)
                        #pragma unroll
                        for (int r = 0; r < 4; r++) { sS[t][r] = 0.f; sD[t][r] = 0.f; }
                }
                floatx4 acc0 = {0.f, 0.f, 0.f, 0.f};
                floatx4 acc1 = {0.f, 0.f, 0.f, 0.f};
                const unsigned short* wp = lwt + (c2 * 16 + lrow) * WROW + quad * 8;
                #pragma unroll
                for (int q = 0; q < 4; q++) {
                    short8 bb = *(const short8*)(wp + q * 32);
                    acc0 = __builtin_amdgcn_mfma_f32_16x16x32_bf16(a[0][q], bb, acc0, 0, 0, 0);
                    acc1 = __builtin_amdgcn_mfma_f32_16x16x32_bf16(a[1][q], bb, acc1, 0, 0, 0);
                }
                #pragma unroll
                for (int r = 0; r < 4; r++) {         // C/D: col=lane&15, row=quad*4+reg
                    int orow = row0w + quad * 4 + r;
                    if (orow < NN) h[(long long)orow * HC + ct * 16 + lrow] = f2bf(acc0[r]);
                    int orow1 = orow + 16;
                    if (orow1 < NN) h[(long long)orow1 * HC + ct * 16 + lrow] = f2bf(acc1[r]);
                }
                float tS = attc[ct * 16 + lrow];
                float tD = attc[256 + ct * 16 + lrow];
                #pragma unroll
                for (int r = 0; r < 4; r++) {
                    sS[0][r] += acc0[r] * tS;  sS[1][r] += acc1[r] * tS;
                    sD[0][r] += acc0[r] * tD;  sD[1][r] += acc1[r] * tD;
                }
                if (c2 & 1) {
                    #pragma unroll
                    for (int m = 1; m <= 8; m <<= 1)
                        #pragma unroll
                        for (int t = 0; t < 2; t++)
                            #pragma unroll
                            for (int r = 0; r < 4; r++) {
                                sS[t][r] += __shfl_xor(sS[t][r], m);
                                sD[t][r] += __shfl_xor(sD[t][r], m);
                            }
                    int hd = ct >> 1;
                    if (lrow < 8) {
                        int t2 = lrow >> 2, rr = lrow & 3;
                        int row = row0w + t2 * 16 + quad * 4 + rr;
                        if (row < NN) a_src[row * NH + hd] = sel8(sS, t2, rr);
                    } else {
                        int lr = lrow - 8;
                        int t2 = lr >> 2, rr = lr & 3;
                        int row = row0w + t2 * 16 + quad * 4 + rr;
                        if (row < NN) a_dst[row * NH + hd] = sel8(sD, t2, rr);
                    }
                }
            }
        }
    } else {
        // histogram over edges (617 blocks)
        for (int e = (b - NT) * 256 + tid; e < NE; e += (NBLK - NT) * 256)
            atomicAdd(&ptr[lde(ei, i64, e)], 1);
    }
    gridbar(bar, 1);

    // ---- P2a: chunk sums (blocks < NBCH, chunk=128) ----
    if (b < NBCH) {
        int base = b * 128;
        int v = (tid < 128 && base + tid < NN) ? ptr[base + tid] : 0;
        #pragma unroll
        for (int off = 32; off >= 1; off >>= 1) v += __shfl_down(v, off);
        if (tid == 0) ssc[0] = v;
        if (tid == 64) ssc[1] = v;
        __syncthreads();
        if (tid == 0) bsum[b] = ssc[0] + ssc[1];
    }
    gridbar(bar, 2);

    // ---- P2b: block 0 wave 0: exclusive scan of bsum[0..NBCH) ----
    if (b == 0 && tid < 64) {
        int run = 0;
        for (int i = 0; i < 7; i++) {          // 7*64 = 448 >= NBCH
            int idx = i * 64 + tid;
            int v = (idx < NBCH) ? bsum[idx] : 0;
            int inc = v;
            #pragma unroll
            for (int d = 1; d < 64; d <<= 1) { int u = __shfl_up(inc, d); if (tid >= d) inc += u; }
            if (idx < NBCH) bsum[idx] = run + inc - v;
            run += __shfl(inc, 63);
        }
    }
    gridbar(bar, 3);

    // ---- P2c: chunk exclusive rescan -> ptr offsets ----
    if (b < NBCH) {
        int base = b * 128;
        int v = (tid < 128 && base + tid < NN) ? ptr[base + tid] : 0;
        int inc = v;
        #pragma unroll
        for (int d = 1; d < 64; d <<= 1) { int u = __shfl_up(inc, d); if ((tid & 63) >= d) inc += u; }
        if ((tid & 63) == 63) ssc[2 + (tid >> 6)] = inc;
        __syncthreads();
        int add = (tid >= 64 && tid < 128) ? ssc[2] : 0;
        if (tid < 128 && base + tid < NN) ptr[base + tid] = bsum[b] + add + inc - v;
    }
    gridbar(bar, 4);

    // ---- P3: CSR fill: entry = src(16b) | keep-mask(8b)<<16; ptr -> end offsets ----
    for (int e = b * 256 + tid; e < NE; e += NBLK * 256) {
        int dst = lde(ei, i64, e);
        int src = lde(ei, i64, (long long)NE + e);
        unsigned int msk = 0;
        if (f32) {
            const floatx4* dp = (const floatx4*)((const float*)dpm + (long long)e * 8);
            floatx4 d0 = dp[0], d1 = dp[1];
            #pragma unroll
            for (int j = 0; j < 4; j++) {
                msk |= (d0[j] != 0.f ? 1u : 0u) << j;
                msk |= (d1[j] != 0.f ? 1u : 0u) << (4 + j);
            }
        } else {
            short8 dd = *(const short8*)((const unsigned short*)dpm + (long long)e * 8);
            #pragma unroll
            for (int j = 0; j < 8; j++) msk |= (dd[j] != 0 ? 1u : 0u) << j;
        }
        int pos = atomicAdd(&ptr[dst], 1);
        csr[pos] = (unsigned int)src | (msk << 16);
    }
    gridbar(bar, 5);

    // ---- P4: single-pass softmax + aggregation, one wave per node, unroll-8 ----
    {
        const int lane = tid & 63;
        const int wave = tid >> 6;
        const int hh = lane >> 3;
        const int cb = lane * 4;
        const float bs0 = attc[512 + cb + 0], bs1 = attc[512 + cb + 1];
        const float bs2 = attc[512 + cb + 2], bs3 = attc[512 + cb + 3];
        for (int node = b * 4 + wave; node < NN; node += NBLK * 4) {
            int end = ptr[node];
            int start = (node > 0) ? ptr[node - 1] : 0;
            int cnt = end - start;
            float adst = a_dst[node * NH + hh];
            float dn = 0.f;
            float acc0 = 0.f, acc1 = 0.f, acc2 = 0.f, acc3 = 0.f;

            unsigned int ubuf = (lane < cnt) ? csr[start + lane] : 0u;
            for (int b0 = 0; b0 < cnt; b0 += 64) {
                int nidx = b0 + 64 + lane;
                unsigned int unext = (nidx < cnt) ? csr[start + nidx] : 0u;
                int lim = min(64, cnt - b0);
                int j = 0;
                for (; j + 8 <= lim; j += 8) {
                    unsigned int u[8]; float g[8]; short4v hv[8];
                    #pragma unroll
                    for (int k = 0; k < 8; k++) u[k] = __shfl(ubuf, j + k);
                    #pragma unroll
                    for (int k = 0; k < 8; k++) g[k] = a_src[(int)(u[k] & 0xFFFFu) * NH + hh];
                    #pragma unroll
                    for (int k = 0; k < 8; k++) {
                        hv[k][0] = 0; hv[k][1] = 0; hv[k][2] = 0; hv[k][3] = 0;
                        if ((u[k] >> (16 + hh)) & 1u)
                            hv[k] = *(const short4v*)(h + (long long)(u[k] & 0xFFFFu) * HC + cb);
                    }
                    #pragma unroll
                    for (int k = 0; k < 8; k++) {
                        float w = __expf(lrelu(g[k] + adst));
                        dn += w;
                        float p = w * 2.5f;
                        acc0 += p * bf2f((unsigned short)hv[k][0]);
                        acc1 += p * bf2f((unsigned short)hv[k][1]);
                        acc2 += p * bf2f((unsigned short)hv[k][2]);
                        acc3 += p * bf2f((unsigned short)hv[k][3]);
                    }
                }
                for (; j < lim; j++) {
                    unsigned int u = __shfl(ubuf, j);
                    int src = (int)(u & 0xFFFFu);
                    float w = __expf(lrelu(a_src[src * NH + hh] + adst));
                    dn += w;
                    if ((u >> (16 + hh)) & 1u) {
                        short4v hv = *(const short4v*)(h + (long long)src * HC + cb);
                        float p = w * 2.5f;
                        acc0 += p * bf2f((unsigned short)hv[0]);
                        acc1 += p * bf2f((unsigned short)hv[1]);
                        acc2 += p * bf2f((unsigned short)hv[2]);
                        acc3 += p * bf2f((unsigned short)hv[3]);
                    }
                }
                ubuf = unext;
            }
            { // self-loop
                float wS = __expf(lrelu(a_src[node * NH + hh] + adst));
                dn += wS;
                float pS = wS * ldf(dps, f32, (long long)node * NH + hh);
                short4v hv = *(const short4v*)(h + (long long)node * HC + cb);
                acc0 += pS * bf2f((unsigned short)hv[0]);
                acc1 += pS * bf2f((unsigned short)hv[1]);
                acc2 += pS * bf2f((unsigned short)hv[2]);
                acc3 += pS * bf2f((unsigned short)hv[3]);
            }
            float inv = 1.0f / dn;
            if (f32) {
                floatx4 o = {acc0 * inv + bs0, acc1 * inv + bs1, acc2 * inv + bs2, acc3 * inv + bs3};
                *(floatx4*)((float*)out + (long long)node * HC + cb) = o;
            } else {
                short4v o;
                o[0] = (short)f2bf(acc0 * inv + bs0);
                o[1] = (short)f2bf(acc1 * inv + bs1);
                o[2] = (short)f2bf(acc2 * inv + bs2);
                o[3] = (short)f2bf(acc3 * inv + bs3);
                *(short4v*)((unsigned short*)out + (long long)node * HC + cb) = o;
            }
        }
    }
}

extern "C" void kernel_launch(void* const* d_in, const int* in_sizes, int n_in,
                              void* d_out, int out_size, void* d_ws, size_t ws_size,
                              hipStream_t stream) {
    const void* x       = d_in[0];
    const int*  ei      = (const int*)d_in[1];
    const void* dp_mask = d_in[2];
    const void* dp_self = d_in[3];
    const void* W       = d_in[4];
    const void* att_s   = d_in[5];
    const void* att_d   = d_in[6];
    const void* bias    = d_in[7];

    char* w = (char*)d_ws;
    unsigned short* h     = (unsigned short*)(w + 0);              // 25,600,000
    float*          a_src = (float*)(w + 25600000);                //  1,600,000
    float*          a_dst = (float*)(w + 27200000);                //  1,600,000
    int*            ptr   = (int*)(w + 28800000);                  //    200,704
    unsigned short* wt    = (unsigned short*)(w + 29000704);       //     65,536
    float*          attc  = (float*)(w + 29066240);                //      4,096
    int*            bsum  = (int*)(w + 29070336);                  //      2,048
    unsigned int*   bar   = (unsigned int*)(w + 29072384);         //         64
    unsigned int*   csr   = (unsigned int*)(w + 29072448);         //  3,200,000
                                                                   // end 32,272,448 B

    hipMemsetAsync(bar, 0, 64, stream);
    k_fused<<<NBLK, 256, 0, stream>>>(x, ei, dp_mask, dp_self, W, att_s, att_d, bias,
                                      h, a_src, a_dst, ptr, wt, attc, bsum, csr, bar, d_out);
}

// Round 6
// 1132.379 us; speedup vs baseline: 1.2519x; 1.2519x over previous
//
#include <hip/hip_runtime.h>

#define NN 50000
#define FIN 128
#define HC 256
#define NH 8
#define NE 800000
#define WROW 136          // padded LDS row (shorts)
#define NBLK 1008         // 4 blocks/CU x 252 CUs  (capacity 1024 at launch_bounds(256,4))
#define NT 391            // gemm tiles of 128 rows
#define NBCH 391          // scan chunks of 128

typedef __attribute__((ext_vector_type(8))) short short8;
typedef __attribute__((ext_vector_type(4))) short short4v;
typedef __attribute__((ext_vector_type(4))) float floatx4;

__device__ __forceinline__ float bf2f(unsigned short u) {
    union { unsigned int i; float f; } v; v.i = ((unsigned int)u) << 16; return v.f;
}
__device__ __forceinline__ unsigned short f2bf(float f) {
    union { float f; unsigned int i; } v; v.f = f;
    unsigned int r = v.i + 0x7fffu + ((v.i >> 16) & 1u);
    return (unsigned short)(r >> 16);
}
__device__ __forceinline__ float lrelu(float x) { return x > 0.f ? x : 0.2f * x; }
__device__ __forceinline__ float ldf(const void* p, int f32, long long i) {
    return f32 ? ((const float*)p)[i] : bf2f(((const unsigned short*)p)[i]);
}
__device__ __forceinline__ int lde(const int* ei, int i64, long long i) {
    return i64 ? (int)((const long long*)ei)[i] : ei[i];
}
__device__ __forceinline__ float sel8(const float s[2][4], int t2, int rr) {
    float a0 = t2 ? s[1][0] : s[0][0];
    float a1 = t2 ? s[1][1] : s[0][1];
    float a2 = t2 ? s[1][2] : s[0][2];
    float a3 = t2 ? s[1][3] : s[0][3];
    return (rr == 0) ? a0 : ((rr == 1) ? a1 : ((rr == 2) ? a2 : a3));
}

// grid barrier. CRITICAL: spin with RELAXED loads — an agent-scope ACQUIRE load
// emits a full cache invalidate per iteration, which thrashes every co-resident
// block's L1/L2 (R5: 1418 us, VALUBusy 3.7%). Acquire exactly once after exit.
__device__ __forceinline__ void gridbar(unsigned int* bar, int slot) {
    __syncthreads();
    if (threadIdx.x == 0) {
        __threadfence();   // release: write back dirty L2 before signaling
        __hip_atomic_fetch_add(&bar[slot], 1u, __ATOMIC_RELAXED, __HIP_MEMORY_SCOPE_AGENT);
        while (__hip_atomic_load(&bar[slot], __ATOMIC_RELAXED, __HIP_MEMORY_SCOPE_AGENT) < (unsigned)gridDim.x)
            __builtin_amdgcn_s_sleep(16);
    }
    __syncthreads();
    __threadfence();       // acquire: one invalidate, now that all data is published
}

__global__ __launch_bounds__(256, 4) void k_fused(
        const void* __restrict__ x, const int* __restrict__ ei,
        const void* __restrict__ dpm, const void* __restrict__ dps,
        const void* __restrict__ W, const void* __restrict__ as_,
        const void* __restrict__ ad_, const void* __restrict__ bs_,
        unsigned short* __restrict__ h, float* __restrict__ a_src,
        float* __restrict__ a_dst, int* __restrict__ ptr,
        unsigned short* __restrict__ wt, float* __restrict__ attc,
        int* __restrict__ bsum, unsigned int* __restrict__ csr,
        unsigned int* __restrict__ bar, void* __restrict__ out) {
    __shared__ unsigned short lwt[128 * WROW];   // 34,816 B (4 blocks/CU fit in 160K)
    __shared__ int ssc[4];
    __shared__ int s_bad, s_nz;

    const int tid = threadIdx.x;
    const int b = blockIdx.x;

    // ---- local dtype flags (every block; reads same leading words, L2-broadcast) ----
    if (tid == 0) { s_bad = 0; s_nz = 0; }
    __syncthreads();
    {
        unsigned int wv = ((const unsigned int*)dpm)[tid];     // fp32 dp_mask words: 0 or 2.5f
        if (wv != 0u && wv != 0x40200000u) atomicAdd(&s_bad, 1);
        if (((const unsigned int*)ei)[2 * tid + 1] != 0u) atomicAdd(&s_nz, 1);
    }
    __syncthreads();
    const int f32 = (s_bad == 0) ? 1 : 0;
    const int i64 = (s_nz == 0) ? 1 : 0;

    // ---- P0: zero ptr; canonicalize W^T (bf16) + attc (fp32) ----
    for (int i = b * 256 + tid; i < NN; i += NBLK * 256) ptr[i] = 0;
    for (int idx = b * 256 + tid; idx < FIN * HC + 768; idx += NBLK * 256) {
        if (idx < FIN * HC) {
            int c = idx >> 7, k = idx & 127;
            wt[idx] = f2bf(ldf(W, f32, (long long)k * HC + c));
        } else {
            int j = idx - FIN * HC;
            if (j < 256)      attc[j] = ldf(as_, f32, j);
            else if (j < 512) attc[j] = ldf(ad_, f32, j - 256);
            else              attc[j] = ldf(bs_, f32, j - 512);
        }
    }
    gridbar(bar, 0);

    // ---- P1: blocks < NT do GEMM+scores tile; blocks >= NT do degree histogram ----
    if (b < NT) {
        const int lane = tid & 63;
        const int wave = tid >> 6;
        const int lrow = lane & 15;
        const int quad = lane >> 4;
        const int row0w = b * 128 + wave * 32;

        short8 a[2][4];
        #pragma unroll
        for (int t = 0; t < 2; t++)
            #pragma unroll
            for (int q = 0; q < 4; q++)
                #pragma unroll
                for (int j = 0; j < 8; j++) a[t][q][j] = 0;

        #pragma unroll
        for (int t = 0; t < 2; t++) {
            int row = row0w + t * 16 + lrow;
            if (row < NN) {
                if (f32) {
                    const float* xp = (const float*)x + (long long)row * FIN + quad * 8;
                    #pragma unroll
                    for (int q = 0; q < 4; q++) {
                        floatx4 u0 = *(const floatx4*)(xp + q * 32);
                        floatx4 u1 = *(const floatx4*)(xp + q * 32 + 4);
                        #pragma unroll
                        for (int j = 0; j < 4; j++) {
                            a[t][q][j]     = (short)f2bf(u0[j]);
                            a[t][q][j + 4] = (short)f2bf(u1[j]);
                        }
                    }
                } else {
                    const unsigned short* xp = (const unsigned short*)x + (long long)row * FIN + quad * 8;
                    #pragma unroll
                    for (int q = 0; q < 4; q++) a[t][q] = *(const short8*)(xp + q * 32);
                }
            }
        }

        float sS[2][4], sD[2][4];
        for (int st = 0; st < 2; st++) {       // two 128-col stages of W in LDS
            __syncthreads();
            {   // copy wt rows [st*128, st*128+128) -> lwt
                int r = tid >> 1, half = tid & 1;
                const short8* s8 = (const short8*)(wt + ((long long)(st * 128 + r)) * FIN + half * 64);
                short8* d8 = (short8*)(lwt + r * WROW + half * 64);
                #pragma unroll
                for (int j = 0; j < 8; j++) d8[j] = s8[j];
            }
            __syncthreads();
            #pragma unroll
            for (int c2 = 0; c2 < 8; c2++) {
                int ct = st * 8 + c2;
                if ((c2 & 1) == 0) {
                    #pragma unroll
                    for (int t = 0; t < 2; t++)
                        #pragma unroll
                        for (int r = 0; r < 4; r++) { sS[t][r] = 0.f; sD[t][r] = 0.f; }
                }
                floatx4 acc0 = {0.f, 0.f, 0.f, 0.f};
                floatx4 acc1 = {0.f, 0.f, 0.f, 0.f};
                const unsigned short* wp = lwt + (c2 * 16 + lrow) * WROW + quad * 8;
                #pragma unroll
                for (int q = 0; q < 4; q++) {
                    short8 bb = *(const short8*)(wp + q * 32);
                    acc0 = __builtin_amdgcn_mfma_f32_16x16x32_bf16(a[0][q], bb, acc0, 0, 0, 0);
                    acc1 = __builtin_amdgcn_mfma_f32_16x16x32_bf16(a[1][q], bb, acc1, 0, 0, 0);
                }
                #pragma unroll
                for (int r = 0; r < 4; r++) {         // C/D: col=lane&15, row=quad*4+reg
                    int orow = row0w + quad * 4 + r;
                    if (orow < NN) h[(long long)orow * HC + ct * 16 + lrow] = f2bf(acc0[r]);
                    int orow1 = orow + 16;
                    if (orow1 < NN) h[(long long)orow1 * HC + ct * 16 + lrow] = f2bf(acc1[r]);
                }
                float tS = attc[ct * 16 + lrow];
                float tD = attc[256 + ct * 16 + lrow];
                #pragma unroll
                for (int r = 0; r < 4; r++) {
                    sS[0][r] += acc0[r] * tS;  sS[1][r] += acc1[r] * tS;
                    sD[0][r] += acc0[r] * tD;  sD[1][r] += acc1[r] * tD;
                }
                if (c2 & 1) {
                    #pragma unroll
                    for (int m = 1; m <= 8; m <<= 1)
                        #pragma unroll
                        for (int t = 0; t < 2; t++)
                            #pragma unroll
                            for (int r = 0; r < 4; r++) {
                                sS[t][r] += __shfl_xor(sS[t][r], m);
                                sD[t][r] += __shfl_xor(sD[t][r], m);
                            }
                    int hd = ct >> 1;
                    if (lrow < 8) {
                        int t2 = lrow >> 2, rr = lrow & 3;
                        int row = row0w + t2 * 16 + quad * 4 + rr;
                        if (row < NN) a_src[row * NH + hd] = sel8(sS, t2, rr);
                    } else {
                        int lr = lrow - 8;
                        int t2 = lr >> 2, rr = lr & 3;
                        int row = row0w + t2 * 16 + quad * 4 + rr;
                        if (row < NN) a_dst[row * NH + hd] = sel8(sD, t2, rr);
                    }
                }
            }
        }
    } else {
        // histogram over edges (617 blocks)
        for (int e = (b - NT) * 256 + tid; e < NE; e += (NBLK - NT) * 256)
            atomicAdd(&ptr[lde(ei, i64, e)], 1);
    }
    gridbar(bar, 1);

    // ---- P2a: chunk sums (blocks < NBCH, chunk=128) ----
    if (b < NBCH) {
        int base = b * 128;
        int v = (tid < 128 && base + tid < NN) ? ptr[base + tid] : 0;
        #pragma unroll
        for (int off = 32; off >= 1; off >>= 1) v += __shfl_down(v, off);
        if (tid == 0) ssc[0] = v;
        if (tid == 64) ssc[1] = v;
        __syncthreads();
        if (tid == 0) bsum[b] = ssc[0] + ssc[1];
    }
    gridbar(bar, 2);

    // ---- P2b: block 0 wave 0: exclusive scan of bsum[0..NBCH) ----
    if (b == 0 && tid < 64) {
        int run = 0;
        for (int i = 0; i < 7; i++) {          // 7*64 = 448 >= NBCH
            int idx = i * 64 + tid;
            int v = (idx < NBCH) ? bsum[idx] : 0;
            int inc = v;
            #pragma unroll
            for (int d = 1; d < 64; d <<= 1) { int u = __shfl_up(inc, d); if (tid >= d) inc += u; }
            if (idx < NBCH) bsum[idx] = run + inc - v;
            run += __shfl(inc, 63);
        }
    }
    gridbar(bar, 3);

    // ---- P2c: chunk exclusive rescan -> ptr offsets ----
    if (b < NBCH) {
        int base = b * 128;
        int v = (tid < 128 && base + tid < NN) ? ptr[base + tid] : 0;
        int inc = v;
        #pragma unroll
        for (int d = 1; d < 64; d <<= 1) { int u = __shfl_up(inc, d); if ((tid & 63) >= d) inc += u; }
        if ((tid & 63) == 63) ssc[2 + (tid >> 6)] = inc;
        __syncthreads();
        int add = (tid >= 64 && tid < 128) ? ssc[2] : 0;
        if (tid < 128 && base + tid < NN) ptr[base + tid] = bsum[b] + add + inc - v;
    }
    gridbar(bar, 4);

    // ---- P3: CSR fill: entry = src(16b) | keep-mask(8b)<<16; ptr -> end offsets ----
    for (int e = b * 256 + tid; e < NE; e += NBLK * 256) {
        int dst = lde(ei, i64, e);
        int src = lde(ei, i64, (long long)NE + e);
        unsigned int msk = 0;
        if (f32) {
            const floatx4* dp = (const floatx4*)((const float*)dpm + (long long)e * 8);
            floatx4 d0 = dp[0], d1 = dp[1];
            #pragma unroll
            for (int j = 0; j < 4; j++) {
                msk |= (d0[j] != 0.f ? 1u : 0u) << j;
                msk |= (d1[j] != 0.f ? 1u : 0u) << (4 + j);
            }
        } else {
            short8 dd = *(const short8*)((const unsigned short*)dpm + (long long)e * 8);
            #pragma unroll
            for (int j = 0; j < 8; j++) msk |= (dd[j] != 0 ? 1u : 0u) << j;
        }
        int pos = atomicAdd(&ptr[dst], 1);
        csr[pos] = (unsigned int)src | (msk << 16);
    }
    gridbar(bar, 5);

    // ---- P4: single-pass softmax + aggregation, one wave per node, unroll-8 ----
    {
        const int lane = tid & 63;
        const int wave = tid >> 6;
        const int hh = lane >> 3;
        const int cb = lane * 4;
        const float bs0 = attc[512 + cb + 0], bs1 = attc[512 + cb + 1];
        const float bs2 = attc[512 + cb + 2], bs3 = attc[512 + cb + 3];
        for (int node = b * 4 + wave; node < NN; node += NBLK * 4) {
            int end = ptr[node];
            int start = (node > 0) ? ptr[node - 1] : 0;
            int cnt = end - start;
            float adst = a_dst[node * NH + hh];
            float dn = 0.f;
            float acc0 = 0.f, acc1 = 0.f, acc2 = 0.f, acc3 = 0.f;

            unsigned int ubuf = (lane < cnt) ? csr[start + lane] : 0u;
            for (int b0 = 0; b0 < cnt; b0 += 64) {
                int nidx = b0 + 64 + lane;
                unsigned int unext = (nidx < cnt) ? csr[start + nidx] : 0u;
                int lim = min(64, cnt - b0);
                int j = 0;
                for (; j + 8 <= lim; j += 8) {
                    unsigned int u[8]; float g[8]; short4v hv[8];
                    #pragma unroll
                    for (int k = 0; k < 8; k++) u[k] = __shfl(ubuf, j + k);
                    #pragma unroll
                    for (int k = 0; k < 8; k++) g[k] = a_src[(int)(u[k] & 0xFFFFu) * NH + hh];
                    #pragma unroll
                    for (int k = 0; k < 8; k++) {
                        hv[k][0] = 0; hv[k][1] = 0; hv[k][2] = 0; hv[k][3] = 0;
                        if ((u[k] >> (16 + hh)) & 1u)
                            hv[k] = *(const short4v*)(h + (long long)(u[k] & 0xFFFFu) * HC + cb);
                    }
                    #pragma unroll
                    for (int k = 0; k < 8; k++) {
                        float w = __expf(lrelu(g[k] + adst));
                        dn += w;
                        float p = w * 2.5f;
                        acc0 += p * bf2f((unsigned short)hv[k][0]);
                        acc1 += p * bf2f((unsigned short)hv[k][1]);
                        acc2 += p * bf2f((unsigned short)hv[k][2]);
                        acc3 += p * bf2f((unsigned short)hv[k][3]);
                    }
                }
                for (; j < lim; j++) {
                    unsigned int u = __shfl(ubuf, j);
                    int src = (int)(u & 0xFFFFu);
                    float w = __expf(lrelu(a_src[src * NH + hh] + adst));
                    dn += w;
                    if ((u >> (16 + hh)) & 1u) {
                        short4v hv = *(const short4v*)(h + (long long)src * HC + cb);
                        float p = w * 2.5f;
                        acc0 += p * bf2f((unsigned short)hv[0]);
                        acc1 += p * bf2f((unsigned short)hv[1]);
                        acc2 += p * bf2f((unsigned short)hv[2]);
                        acc3 += p * bf2f((unsigned short)hv[3]);
                    }
                }
                ubuf = unext;
            }
            { // self-loop
                float wS = __expf(lrelu(a_src[node * NH + hh] + adst));
                dn += wS;
                float pS = wS * ldf(dps, f32, (long long)node * NH + hh);
                short4v hv = *(const short4v*)(h + (long long)node * HC + cb);
                acc0 += pS * bf2f((unsigned short)hv[0]);
                acc1 += pS * bf2f((unsigned short)hv[1]);
                acc2 += pS * bf2f((unsigned short)hv[2]);
                acc3 += pS * bf2f((unsigned short)hv[3]);
            }
            float inv = 1.0f / dn;
            if (f32) {
                floatx4 o = {acc0 * inv + bs0, acc1 * inv + bs1, acc2 * inv + bs2, acc3 * inv + bs3};
                *(floatx4*)((float*)out + (long long)node * HC + cb) = o;
            } else {
                short4v o;
                o[0] = (short)f2bf(acc0 * inv + bs0);
                o[1] = (short)f2bf(acc1 * inv + bs1);
                o[2] = (short)f2bf(acc2 * inv + bs2);
                o[3] = (short)f2bf(acc3 * inv + bs3);
                *(short4v*)((unsigned short*)out + (long long)node * HC + cb) = o;
            }
        }
    }
}

extern "C" void kernel_launch(void* const* d_in, const int* in_sizes, int n_in,
                              void* d_out, int out_size, void* d_ws, size_t ws_size,
                              hipStream_t stream) {
    const void* x       = d_in[0];
    const int*  ei      = (const int*)d_in[1];
    const void* dp_mask = d_in[2];
    const void* dp_self = d_in[3];
    const void* W       = d_in[4];
    const void* att_s   = d_in[5];
    const void* att_d   = d_in[6];
    const void* bias    = d_in[7];

    char* w = (char*)d_ws;
    unsigned short* h     = (unsigned short*)(w + 0);              // 25,600,000
    float*          a_src = (float*)(w + 25600000);                //  1,600,000
    float*          a_dst = (float*)(w + 27200000);                //  1,600,000
    int*            ptr   = (int*)(w + 28800000);                  //    200,704
    unsigned short* wt    = (unsigned short*)(w + 29000704);       //     65,536
    float*          attc  = (float*)(w + 29066240);                //      4,096
    int*            bsum  = (int*)(w + 29070336);                  //      2,048
    unsigned int*   bar   = (unsigned int*)(w + 29072384);         //         64
    unsigned int*   csr   = (unsigned int*)(w + 29072448);         //  3,200,000
                                                                   // end 32,272,448 B

    hipMemsetAsync(bar, 0, 64, stream);
    k_fused<<<NBLK, 256, 0, stream>>>(x, ei, dp_mask, dp_self, W, att_s, att_d, bias,
                                      h, a_src, a_dst, ptr, wt, attc, bsum, csr, bar, d_out);
}

// Round 7
// 227.760 us; speedup vs baseline: 6.2242x; 4.9718x over previous
//
#include <hip/hip_runtime.h>

#define NN 50000
#define FIN 128
#define HC 256
#define NH 8
#define NE 800000
#define WROW 136        // padded LDS row (shorts); rows 16B-aligned
#define GEMMB 391       // 391 * 128 rows >= NN
#define NBLK1 3516      // 391 gemm + 3125 fill (3125*256 == NE exactly)
#define OVFCAP 131072

typedef __attribute__((ext_vector_type(8))) short short8;
typedef __attribute__((ext_vector_type(4))) short short4v;
typedef __attribute__((ext_vector_type(4))) float floatx4;

__device__ __forceinline__ float bf2f(unsigned short u) {
    union { unsigned int i; float f; } v; v.i = ((unsigned int)u) << 16; return v.f;
}
__device__ __forceinline__ unsigned short f2bf(float f) {
    union { float f; unsigned int i; } v; v.f = f;
    unsigned int r = v.i + 0x7fffu + ((v.i >> 16) & 1u);
    return (unsigned short)(r >> 16);
}
__device__ __forceinline__ float lrelu(float x) { return x > 0.f ? x : 0.2f * x; }
__device__ __forceinline__ float ldf(const void* p, int f32, long long i) {
    return f32 ? ((const float*)p)[i] : bf2f(((const unsigned short*)p)[i]);
}
__device__ __forceinline__ int lde(const int* ei, int i64, long long i) {
    return i64 ? (int)((const long long*)ei)[i] : ei[i];
}
__device__ __forceinline__ float sel8(const float s[2][4], int t2, int rr) {
    float a0 = t2 ? s[1][0] : s[0][0];
    float a1 = t2 ? s[1][1] : s[0][1];
    float a2 = t2 ? s[1][2] : s[0][2];
    float a3 = t2 ? s[1][3] : s[0][3];
    return (rr == 0) ? a0 : ((rr == 1) ? a1 : ((rr == 2) ? a2 : a3));
}

// ---- K1: blocks < GEMMB: MFMA GEMM + attention scores.
//          blocks >= GEMMB: bucket-fill (atomic slot alloc, no scan needed).
__global__ __launch_bounds__(256) void k_front(
        const void* __restrict__ x, const int* __restrict__ ei,
        const void* __restrict__ dpm, const void* __restrict__ W,
        const void* __restrict__ as_, const void* __restrict__ ad_,
        int* __restrict__ flags, unsigned short* __restrict__ h,
        float* __restrict__ a_src, float* __restrict__ a_dst,
        int* __restrict__ cnt, int* __restrict__ ovfcnt,
        unsigned int* __restrict__ bucket, int2* __restrict__ ovf, int cap) {
    __shared__ unsigned short lwt[256 * WROW];   // 69,632 B
    __shared__ int s_bad, s_nz;
    const int tid = threadIdx.x;
    const int b = blockIdx.x;

    // dtype probe (local per block; leading words are L2-hot)
    if (tid == 0) { s_bad = 0; s_nz = 0; }
    __syncthreads();
    {
        unsigned int wv = ((const unsigned int*)dpm)[tid];   // fp32 dp_mask words: 0 or 2.5f
        if (wv != 0u && wv != 0x40200000u) atomicAdd(&s_bad, 1);
        if (((const unsigned int*)ei)[2 * tid + 1] != 0u) atomicAdd(&s_nz, 1);
    }
    __syncthreads();
    const int f32 = (s_bad == 0) ? 1 : 0;
    const int i64 = (s_nz == 0) ? 1 : 0;
    if (b == 0 && tid == 0) { flags[0] = f32; flags[1] = i64; }

    if (b < GEMMB) {
        // ---- stage W^T into LDS: thread tid = output column c; coalesced row reads ----
        {
            if (f32) {
                const float* wp = (const float*)W + tid;
                for (int k = 0; k < FIN; k++) lwt[tid * WROW + k] = f2bf(wp[(long long)k * HC]);
            } else {
                const unsigned short* wp = (const unsigned short*)W + tid;
                for (int k = 0; k < FIN; k++) lwt[tid * WROW + k] = wp[(long long)k * HC];
            }
        }
        __syncthreads();

        const int lane = tid & 63;
        const int wave = tid >> 6;
        const int lrow = lane & 15;
        const int quad = lane >> 4;
        const int row0w = b * 128 + wave * 32;

        short8 a[2][4];
        #pragma unroll
        for (int t = 0; t < 2; t++)
            #pragma unroll
            for (int q = 0; q < 4; q++)
                #pragma unroll
                for (int j = 0; j < 8; j++) a[t][q][j] = 0;

        #pragma unroll
        for (int t = 0; t < 2; t++) {
            int row = row0w + t * 16 + lrow;
            if (row < NN) {
                if (f32) {
                    const float* xp = (const float*)x + (long long)row * FIN + quad * 8;
                    #pragma unroll
                    for (int q = 0; q < 4; q++) {
                        floatx4 u0 = *(const floatx4*)(xp + q * 32);
                        floatx4 u1 = *(const floatx4*)(xp + q * 32 + 4);
                        #pragma unroll
                        for (int j = 0; j < 4; j++) {
                            a[t][q][j]     = (short)f2bf(u0[j]);
                            a[t][q][j + 4] = (short)f2bf(u1[j]);
                        }
                    }
                } else {
                    const unsigned short* xp = (const unsigned short*)x + (long long)row * FIN + quad * 8;
                    #pragma unroll
                    for (int q = 0; q < 4; q++) a[t][q] = *(const short8*)(xp + q * 32);
                }
            }
        }

        float sS[2][4], sD[2][4];
        #pragma unroll 4
        for (int ct = 0; ct < 16; ct++) {
            if ((ct & 1) == 0) {
                #pragma unroll
                for (int t = 0; t < 2; t++)
                    #pragma unroll
                    for (int r = 0; r < 4; r++) { sS[t][r] = 0.f; sD[t][r] = 0.f; }
            }
            floatx4 acc0 = {0.f, 0.f, 0.f, 0.f};
            floatx4 acc1 = {0.f, 0.f, 0.f, 0.f};
            const unsigned short* wp = lwt + (ct * 16 + lrow) * WROW + quad * 8;
            #pragma unroll
            for (int q = 0; q < 4; q++) {
                short8 bb = *(const short8*)(wp + q * 32);
                acc0 = __builtin_amdgcn_mfma_f32_16x16x32_bf16(a[0][q], bb, acc0, 0, 0, 0);
                acc1 = __builtin_amdgcn_mfma_f32_16x16x32_bf16(a[1][q], bb, acc1, 0, 0, 0);
            }
            // C/D: col = lane&15, row = quad*4 + reg
            #pragma unroll
            for (int r = 0; r < 4; r++) {
                int orow = row0w + quad * 4 + r;
                if (orow < NN) h[(long long)orow * HC + ct * 16 + lrow] = f2bf(acc0[r]);
                int orow1 = orow + 16;
                if (orow1 < NN) h[(long long)orow1 * HC + ct * 16 + lrow] = f2bf(acc1[r]);
            }
            float tS = ldf(as_, f32, ct * 16 + lrow);
            float tD = ldf(ad_, f32, ct * 16 + lrow);
            #pragma unroll
            for (int r = 0; r < 4; r++) {
                sS[0][r] += acc0[r] * tS;  sS[1][r] += acc1[r] * tS;
                sD[0][r] += acc0[r] * tD;  sD[1][r] += acc1[r] * tD;
            }
            if (ct & 1) {   // head ct>>1 complete: reduce over 16-lane col group
                #pragma unroll
                for (int m = 1; m <= 8; m <<= 1)
                    #pragma unroll
                    for (int t = 0; t < 2; t++)
                        #pragma unroll
                        for (int r = 0; r < 4; r++) {
                            sS[t][r] += __shfl_xor(sS[t][r], m);
                            sD[t][r] += __shfl_xor(sD[t][r], m);
                        }
                int hd = ct >> 1;
                if (lrow < 8) {
                    int t2 = lrow >> 2, rr = lrow & 3;
                    int row = row0w + t2 * 16 + quad * 4 + rr;
                    if (row < NN) a_src[row * NH + hd] = sel8(sS, t2, rr);
                } else {
                    int lr = lrow - 8;
                    int t2 = lr >> 2, rr = lr & 3;
                    int row = row0w + t2 * 16 + quad * 4 + rr;
                    if (row < NN) a_dst[row * NH + hd] = sel8(sD, t2, rr);
                }
            }
        }
    } else {
        // ---- bucket fill: one edge per thread ----
        int e = (b - GEMMB) * 256 + tid;   // < NE by construction
        int dst = lde(ei, i64, e);
        int src = lde(ei, i64, (long long)NE + e);
        unsigned int msk = 0;
        if (f32) {
            const floatx4* dp = (const floatx4*)((const float*)dpm + (long long)e * 8);
            floatx4 d0 = dp[0], d1 = dp[1];
            #pragma unroll
            for (int j = 0; j < 4; j++) {
                msk |= (d0[j] != 0.f ? 1u : 0u) << j;
                msk |= (d1[j] != 0.f ? 1u : 0u) << (4 + j);
            }
        } else {
            short8 dd = *(const short8*)((const unsigned short*)dpm + (long long)e * 8);
            #pragma unroll
            for (int j = 0; j < 8; j++) msk |= (dd[j] != 0 ? 1u : 0u) << j;
        }
        unsigned int entry = (unsigned int)src | (msk << 16);
        int pos = atomicAdd(&cnt[dst], 1);
        if (pos < cap) bucket[(long long)dst * cap + pos] = entry;
        else {
            int op = atomicAdd(ovfcnt, 1);
            if (op < OVFCAP) ovf[op] = make_int2(dst, (int)entry);
        }
    }
}

// ---- K2: single-pass softmax + aggregation, one wave per node, unroll-8 ----
__global__ __launch_bounds__(256) void k_aggr(
        const int* __restrict__ cnt, const int* __restrict__ ovfcnt,
        const unsigned int* __restrict__ bucket, const int2* __restrict__ ovf,
        const float* __restrict__ a_src, const float* __restrict__ a_dst,
        const unsigned short* __restrict__ h, const void* __restrict__ dps,
        const int* __restrict__ flags, const void* __restrict__ bs_,
        void* __restrict__ out, int cap) {
    int node = blockIdx.x * 4 + (threadIdx.x >> 6);
    int lane = threadIdx.x & 63;
    if (node >= NN) return;
    const int f32 = flags[0];
    int novf = *ovfcnt; novf = novf > OVFCAP ? OVFCAP : novf;
    int c = cnt[node];
    int mn = c < cap ? c : cap;
    long long base = (long long)node * cap;

    const int hh = lane >> 3;
    const int cb = lane * 4;
    float adst = a_dst[node * NH + hh];
    float dn = 0.f;
    float acc0 = 0.f, acc1 = 0.f, acc2 = 0.f, acc3 = 0.f;

    unsigned int ubuf = (lane < mn) ? bucket[base + lane] : 0u;
    for (int b0 = 0; b0 < mn; b0 += 64) {
        int nidx = b0 + 64 + lane;
        unsigned int unext = (nidx < mn) ? bucket[base + nidx] : 0u;
        int lim = min(64, mn - b0);
        int j = 0;
        for (; j + 8 <= lim; j += 8) {
            unsigned int u[8]; float g[8]; short4v hv[8];
            #pragma unroll
            for (int k = 0; k < 8; k++) u[k] = __shfl(ubuf, j + k);
            #pragma unroll
            for (int k = 0; k < 8; k++) g[k] = a_src[(int)(u[k] & 0xFFFFu) * NH + hh];
            #pragma unroll
            for (int k = 0; k < 8; k++) {
                hv[k][0] = 0; hv[k][1] = 0; hv[k][2] = 0; hv[k][3] = 0;
                if ((u[k] >> (16 + hh)) & 1u)
                    hv[k] = *(const short4v*)(h + (long long)(u[k] & 0xFFFFu) * HC + cb);
            }
            #pragma unroll
            for (int k = 0; k < 8; k++) {
                float w = __expf(lrelu(g[k] + adst));
                dn += w;
                float p = w * 2.5f;
                acc0 += p * bf2f((unsigned short)hv[k][0]);
                acc1 += p * bf2f((unsigned short)hv[k][1]);
                acc2 += p * bf2f((unsigned short)hv[k][2]);
                acc3 += p * bf2f((unsigned short)hv[k][3]);
            }
        }
        for (; j < lim; j++) {
            unsigned int u = __shfl(ubuf, j);
            int src = (int)(u & 0xFFFFu);
            float w = __expf(lrelu(a_src[src * NH + hh] + adst));
            dn += w;
            if ((u >> (16 + hh)) & 1u) {
                short4v hv = *(const short4v*)(h + (long long)src * HC + cb);
                float p = w * 2.5f;
                acc0 += p * bf2f((unsigned short)hv[0]);
                acc1 += p * bf2f((unsigned short)hv[1]);
                acc2 += p * bf2f((unsigned short)hv[2]);
                acc3 += p * bf2f((unsigned short)hv[3]);
            }
        }
        ubuf = unext;
    }
    // overflow sweep (novf ~ 0 in practice; correct for any value)
    for (int i = 0; i < novf; i++) {
        int2 tv = ovf[i];
        if (tv.x == node) {
            unsigned int u = (unsigned int)tv.y;
            int src = (int)(u & 0xFFFFu);
            float w = __expf(lrelu(a_src[src * NH + hh] + adst));
            dn += w;
            if ((u >> (16 + hh)) & 1u) {
                short4v hv = *(const short4v*)(h + (long long)src * HC + cb);
                float p = w * 2.5f;
                acc0 += p * bf2f((unsigned short)hv[0]);
                acc1 += p * bf2f((unsigned short)hv[1]);
                acc2 += p * bf2f((unsigned short)hv[2]);
                acc3 += p * bf2f((unsigned short)hv[3]);
            }
        }
    }
    { // self-loop
        float wS = __expf(lrelu(a_src[node * NH + hh] + adst));
        dn += wS;
        float pS = wS * ldf(dps, f32, (long long)node * NH + hh);
        short4v hv = *(const short4v*)(h + (long long)node * HC + cb);
        acc0 += pS * bf2f((unsigned short)hv[0]);
        acc1 += pS * bf2f((unsigned short)hv[1]);
        acc2 += pS * bf2f((unsigned short)hv[2]);
        acc3 += pS * bf2f((unsigned short)hv[3]);
    }
    float inv = 1.0f / dn;
    float b0 = ldf(bs_, f32, cb + 0), b1 = ldf(bs_, f32, cb + 1);
    float b2 = ldf(bs_, f32, cb + 2), b3 = ldf(bs_, f32, cb + 3);
    if (f32) {
        floatx4 o = {acc0 * inv + b0, acc1 * inv + b1, acc2 * inv + b2, acc3 * inv + b3};
        *(floatx4*)((float*)out + (long long)node * HC + cb) = o;
    } else {
        short4v o;
        o[0] = (short)f2bf(acc0 * inv + b0);
        o[1] = (short)f2bf(acc1 * inv + b1);
        o[2] = (short)f2bf(acc2 * inv + b2);
        o[3] = (short)f2bf(acc3 * inv + b3);
        *(short4v*)((unsigned short*)out + (long long)node * HC + cb) = o;
    }
}

extern "C" void kernel_launch(void* const* d_in, const int* in_sizes, int n_in,
                              void* d_out, int out_size, void* d_ws, size_t ws_size,
                              hipStream_t stream) {
    const void* x       = d_in[0];
    const int*  ei      = (const int*)d_in[1];
    const void* dp_mask = d_in[2];
    const void* dp_self = d_in[3];
    const void* W       = d_in[4];
    const void* att_s   = d_in[5];
    const void* att_d   = d_in[6];
    const void* bias    = d_in[7];

    char* w = (char*)d_ws;
    unsigned short* h      = (unsigned short*)(w + 0);             // 25,600,000
    float*          a_src  = (float*)(w + 25600000);               //  1,600,000
    float*          a_dst  = (float*)(w + 27200000);               //  1,600,000
    int*            cnt    = (int*)(w + 28800000);                 //    200,000
    int*            ovfcnt = (int*)(w + 29000000);                 //          4
    int*            flags  = (int*)(w + 29000064);                 //          8
    int2*           ovf    = (int2*)(w + 29000960);                //  1,048,576
    unsigned int*   bucket = (unsigned int*)(w + 30049536);        //  cap*200,000

    long long avail = (long long)ws_size - 30049536LL;
    int cap = (int)(avail / 200000LL);
    if (cap > 64) cap = 64;
    if (cap < 4) cap = 4;

    // zero cnt + ovfcnt (+flags; flags rewritten by k_front before k_aggr reads)
    hipMemsetAsync(cnt, 0, 200960, stream);
    k_front<<<NBLK1, 256, 0, stream>>>(x, ei, dp_mask, W, att_s, att_d,
                                       flags, h, a_src, a_dst, cnt, ovfcnt, bucket, ovf, cap);
    k_aggr<<<NN / 4, 256, 0, stream>>>(cnt, ovfcnt, bucket, ovf, a_src, a_dst, h,
                                       dp_self, flags, bias, d_out, cap);
}